// Round 10
// baseline (247.288 us; speedup 1.0000x reference)
//
#include <hip/hip_runtime.h>
#include <hip/hip_bf16.h>

#define S_LEN 2048
#define D_DIM 1024
#define NBATCH 4

typedef __attribute__((ext_vector_type(4)))  float f32x4;
typedef __attribute__((ext_vector_type(8)))  short s16x8;   // MFMA bf16 operand
typedef __attribute__((ext_vector_type(4)))  unsigned short u16x4;

__device__ __forceinline__ unsigned short f2b(float f) {
    __hip_bfloat16 h = __float2bfloat16(f);
    return __builtin_bit_cast(unsigned short, h);
}

// Direct global->LDS DMA, 16 bytes per lane. LDS dest: wave-uniform base + lane*16.
__device__ __forceinline__ void load_lds16(const unsigned short* g, unsigned short* l) {
    __builtin_amdgcn_global_load_lds(
        (const __attribute__((address_space(1))) void*)(g),
        (__attribute__((address_space(3))) void*)(l), 16, 0, 0);
}

// ---------------------------------------------------------------------------
__global__ __launch_bounds__(256)
void cvt_kernel(const float* __restrict__ in, unsigned short* __restrict__ out) {
    long i = ((long)blockIdx.x * 256 + threadIdx.x) * 4;
    f32x4 v = *(const f32x4*)(in + i);
    u16x4 o;
    o.x = f2b(v.x); o.y = f2b(v.y); o.z = f2b(v.z); o.w = f2b(v.w);
    *(u16x4*)(out + i) = o;
}

// ---------------------------------------------------------------------------
__global__ __launch_bounds__(256)
void transW_kernel(const float* __restrict__ W0, const float* __restrict__ W1,
                   const float* __restrict__ W2, unsigned short* __restrict__ WT) {
    const float* W = (blockIdx.z == 0) ? W0 : (blockIdx.z == 1) ? W1 : W2;
    unsigned short* O = WT + (long)blockIdx.z * 1024 * 1024;
    __shared__ float t[32][33];
    int tid = threadIdx.x;
    int r  = tid >> 3;
    int c4 = tid & 7;
    int bi = blockIdx.x, bj = blockIdx.y;
    f32x4 v = *(const f32x4*)&W[(long)(bi * 32 + r) * 1024 + bj * 32 + c4 * 4];
    t[r][c4 * 4 + 0] = v.x; t[r][c4 * 4 + 1] = v.y;
    t[r][c4 * 4 + 2] = v.z; t[r][c4 * 4 + 3] = v.w;
    __syncthreads();
    u16x4 o;
    o.x = f2b(t[c4 * 4 + 0][r]); o.y = f2b(t[c4 * 4 + 1][r]);
    o.z = f2b(t[c4 * 4 + 2][r]); o.w = f2b(t[c4 * 4 + 3][r]);
    *(u16x4*)&O[(long)(bj * 32 + r) * 1024 + bi * 32 + c4 * 4] = o;
}

// ---------------------------------------------------------------------------
// Kernel A: 256x256 tile, 8 waves (2M x 4N), wave-tile 128x64 = 8x4 frags
// (0.023 B/FLOP LDS ratio, under the 128 B/cyc port budget). BK=32.
// Triple-buffered counted-vmcnt pipeline (proven in round 9): per tile
//   wait vmcnt(4) -> s_barrier -> stage(t+2) (4 loads/thread) -> 12 ds_read
//   -> setprio(1) 32 MFMA setprio(0)
// LDS paired-row layout: A-half granule gi: line=gi>>3 (row pair), g8=gi&7;
// element (row,fg) lives at line=row>>1, g8=((row&1)*4+fg)^(line&7).
// Per-16-lane read phase each bank-quad is hit exactly 2x => conflict-free.
// Stage writes are linear (gi = l*512+tid), source address pre-inverse-mapped.
// OMODE: 0 bf16 out, 1 f32 out. CSKIP: skip bn>bm (256x256 causal blocks).
// KRANGE (PV split-K): x<nlo: bm=x, kbeg=0, kend=min((bm+1)*256,kcap), C=out;
//                      x>=nlo: bm=x-nlo+(kcap>>8), kbeg=kcap, kend=(bm+1)*256, C=pv2.
template<int OMODE, bool CSKIP, bool KRANGE>
__global__ __launch_bounds__(512, 2)
void gemm_A(const unsigned short* __restrict__ A, int lda, long aStride,
            const unsigned short* __restrict__ Bt, int ldb, long bStride,
            void* __restrict__ Cv, int ldc, long cStride,
            int K, float alpha, float* __restrict__ pv2, int nlo, int kcap) {
    constexpr int BUF = 16384;   // shorts per buffer (32 KB: A 16KB + B 16KB)
    int bm = blockIdx.x;
    const int bn = blockIdx.y, bz = blockIdx.z;
    if (CSKIP && bn > bm) return;
    int kbeg = 0, kend = K;
    if (KRANGE) {
        if (bm < nlo) { kend = min((bm + 1) * 256, kcap); }
        else          { bm = bm - nlo + (kcap >> 8); kbeg = kcap; kend = (bm + 1) * 256; }
    }
    A  += (long)bz * aStride;
    Bt += (long)bz * bStride;

    const int tid  = threadIdx.x;
    const int lane = tid & 63;
    const int wid  = tid >> 6;          // 0..7
    const int wm   = wid >> 2;          // 0..1  (128-row slab)
    const int wn   = wid & 3;           // 0..3  (64-col slab)

    extern __shared__ __align__(16) unsigned short smem[];   // 3 * BUF

    f32x4 acc[8][4] = {};
    const int nt = (kend - kbeg) >> 5;                       // >= 2 always here

    // staging source precompute: load slot l in {0,1}: granule gi = l*512+tid.
    // line=gi>>3, u=(gi&7)^(line&7): row=line*2+(u>>2), col=(u&3)*8 shorts.
    const int giA0 = tid, giA1 = 512 + tid;
    auto src = [&](const unsigned short* base, int ld, int rbase, int gi) {
        const int line = gi >> 3, u = (gi & 7) ^ (line & 7);
        return base + (long)(rbase + line * 2 + (u >> 2)) * ld + (u & 3) * 8;
    };
    const unsigned short* pa0 = src(A,  lda, bm * 256, giA0);
    const unsigned short* pa1 = src(A,  lda, bm * 256, giA1);
    const unsigned short* pb0 = src(Bt, ldb, bn * 256, giA0);
    const unsigned short* pb1 = src(Bt, ldb, bn * 256, giA1);
    const int dst0 = giA0 * 8, dst1 = giA1 * 8;   // LDS short offsets (linear)

    // read-side per-lane constants
    const int fr  = lane & 15;
    const int fg  = lane >> 4;          // k-group 0..3 (8 shorts each)
    const int fr2 = fr >> 1;
    const int g8r = (((fr & 1) << 2) | fg) ^ fr2;
    const int loff = fr2 * 64 + g8r * 8;           // shorts within line block

    auto stage = [&](int t) {
        const int k0 = kbeg + t * 32;
        unsigned short* d = smem + (t % 3) * BUF;
        load_lds16(pa0 + k0, d + dst0);
        load_lds16(pa1 + k0, d + dst1);
        load_lds16(pb0 + k0, d + 8192 + dst0);
        load_lds16(pb1 + k0, d + 8192 + dst1);
    };

    stage(0);
    stage(1);

    for (int t = 0; t < nt; ++t) {
        if (t + 1 < nt) asm volatile("s_waitcnt vmcnt(4)" ::: "memory");
        else            asm volatile("s_waitcnt vmcnt(0)" ::: "memory");
        __builtin_amdgcn_s_barrier();
        if (t + 2 < nt) stage(t + 2);

        const unsigned short* as = smem + (t % 3) * BUF;
        const unsigned short* bs = as + 8192;
        s16x8 af[8], bf[4];
        #pragma unroll
        for (int m = 0; m < 8; ++m)
            af[m] = *(const s16x8*)&as[(wm * 64 + m * 8) * 64 + loff];
        #pragma unroll
        for (int n = 0; n < 4; ++n)
            bf[n] = *(const s16x8*)&bs[(wn * 32 + n * 8) * 64 + loff];
        __builtin_amdgcn_s_setprio(1);
        #pragma unroll
        for (int m = 0; m < 8; ++m)
            #pragma unroll
            for (int n = 0; n < 4; ++n)
                acc[m][n] = __builtin_amdgcn_mfma_f32_16x16x32_bf16(af[m], bf[n], acc[m][n], 0, 0, 0);
        __builtin_amdgcn_s_setprio(0);
    }

    // epilogue: C/D layout col = lane&15, row = (lane>>4)*4 + reg
    const int crow0 = bm * 256 + wm * 128;
    const int ccol0 = bn * 256 + wn * 64;
    const int cr = (lane >> 4) * 4;
    const int cc = lane & 15;
    if (OMODE == 0) {
        unsigned short* C = (unsigned short*)Cv + (long)bz * cStride;
        #pragma unroll
        for (int m = 0; m < 8; ++m)
            #pragma unroll
            for (int r = 0; r < 4; ++r) {
                const long row = crow0 + m * 16 + cr + r;
                #pragma unroll
                for (int n = 0; n < 4; ++n)
                    C[row * ldc + ccol0 + n * 16 + cc] = f2b(acc[m][n][r] * alpha);
            }
    } else {
        float* C = (KRANGE && blockIdx.x >= nlo) ? (pv2 + (long)bz * cStride)
                                                 : ((float*)Cv + (long)bz * cStride);
        #pragma unroll
        for (int m = 0; m < 8; ++m)
            #pragma unroll
            for (int r = 0; r < 4; ++r) {
                const long row = crow0 + m * 16 + cr + r;
                #pragma unroll
                for (int n = 0; n < 4; ++n)
                    C[row * ldc + ccol0 + n * 16 + cc] = acc[m][n][r] * alpha;
            }
    }
}

// ---------------------------------------------------------------------------
// Kernel B (round-9 structure, V^T only): 128x256, 64x64 wave-tile, BK=64,
// triple-buffer vmcnt(6). Kept for the V^T projection (grid 8x32 = 256 blocks).
__global__ __launch_bounds__(512, 2)
void gemm_B(const unsigned short* __restrict__ A, int lda,
            const unsigned short* __restrict__ Bt, int ldb,
            unsigned short* __restrict__ C, int ldc, int K) {
    constexpr int BUF = (128 + 256) * 64;
    const int bm = blockIdx.x, bn = blockIdx.y;
    const int tid  = threadIdx.x;
    const int lane = tid & 63;
    const int wid  = tid >> 6;
    const int wm   = wid >> 2;
    const int wn   = wid & 3;

    extern __shared__ __align__(16) unsigned short smem[];
    f32x4 acc[4][4] = {};
    const int nt = K / 64;

    const int srl = tid >> 3;
    const int sg  = (tid & 7) ^ (srl & 7);
    const unsigned short* agb = A  + (long)(bm * 128 + srl) * lda + sg * 8;
    const unsigned short* bgb = Bt + (long)(bn * 256 + srl) * ldb + sg * 8;

    const int fr   = lane & 15;
    const int fg   = lane >> 4;
    const int rxor = (fr & 7) * 8;

    auto stage = [&](int t) {
        const int k0 = t * 64;
        unsigned short* d = smem + (t % 3) * BUF;
        #pragma unroll
        for (int i = 0; i < 2; ++i)
            load_lds16(agb + (long)(i * 64) * lda + k0, d + i * 4096 + tid * 8);
        #pragma unroll
        for (int i = 0; i < 4; ++i)
            load_lds16(bgb + (long)(i * 64) * ldb + k0, d + 8192 + i * 4096 + tid * 8);
    };

    stage(0);
    stage(1);

    for (int t = 0; t < nt; ++t) {
        if (t + 1 < nt) asm volatile("s_waitcnt vmcnt(6)" ::: "memory");
        else            asm volatile("s_waitcnt vmcnt(0)" ::: "memory");
        __builtin_amdgcn_s_barrier();
        if (t + 2 < nt) stage(t + 2);

        const unsigned short* as = smem + (t % 3) * BUF;
        const unsigned short* bs = as + 8192;
        #pragma unroll
        for (int ks = 0; ks < 2; ++ks) {
            s16x8 af[4], bf[4];
            #pragma unroll
            for (int m = 0; m < 4; ++m)
                af[m] = *(const s16x8*)&as[(wm * 64 + m * 16 + fr) * 64 + (((ks * 4 + fg) * 8) ^ rxor)];
            #pragma unroll
            for (int n = 0; n < 4; ++n)
                bf[n] = *(const s16x8*)&bs[(wn * 64 + n * 16 + fr) * 64 + (((ks * 4 + fg) * 8) ^ rxor)];
            __builtin_amdgcn_s_setprio(1);
            #pragma unroll
            for (int m = 0; m < 4; ++m)
                #pragma unroll
                for (int n = 0; n < 4; ++n)
                    acc[m][n] = __builtin_amdgcn_mfma_f32_16x16x32_bf16(af[m], bf[n], acc[m][n], 0, 0, 0);
            __builtin_amdgcn_s_setprio(0);
        }
    }

    const int crow0 = bm * 128 + wm * 64;
    const int ccol0 = bn * 256 + wn * 64;
    const int cr = (lane >> 4) * 4;
    const int cc = lane & 15;
    #pragma unroll
    for (int m = 0; m < 4; ++m)
        #pragma unroll
        for (int r = 0; r < 4; ++r) {
            const long row = crow0 + m * 16 + cr + r;
            #pragma unroll
            for (int n = 0; n < 4; ++n)
                C[row * ldc + ccol0 + n * 16 + cc] = f2b(acc[m][n][r]);
        }
}

// ---------------------------------------------------------------------------
// Causal row softmax, in-place fp32 scores row -> bf16 P row (zero-filled past i).
__global__ __launch_bounds__(256)
void softmax_rows(float* __restrict__ scores) {
    const int i = blockIdx.x;
    const int z = blockIdx.y;
    float* row = scores + ((long)z * S_LEN + i) * S_LEN;
    const int c = i + 1;
    const int tid  = threadIdx.x;
    const int lane = tid & 63;
    const int wid  = tid >> 6;

    f32x4 v0 = ((const f32x4*)row)[tid];
    f32x4 v1 = ((const f32x4*)row)[tid + 256];
    const int j0 = tid * 4, j1 = (tid + 256) * 4;

    float m = -3.4e38f;
    #pragma unroll
    for (int e = 0; e < 4; e++) {
        if (j0 + e < c) m = fmaxf(m, v0[e]);
        if (j1 + e < c) m = fmaxf(m, v1[e]);
    }
    #pragma unroll
    for (int off = 32; off > 0; off >>= 1) m = fmaxf(m, __shfl_xor(m, off));
    __shared__ float redm[4];
    if (lane == 0) redm[wid] = m;
    __syncthreads();
    m = fmaxf(fmaxf(redm[0], redm[1]), fmaxf(redm[2], redm[3]));

    float e0[4], e1[4];
    float s = 0.f;
    #pragma unroll
    for (int e = 0; e < 4; e++) {
        e0[e] = (j0 + e < c) ? __expf(v0[e] - m) : 0.f;
        e1[e] = (j1 + e < c) ? __expf(v1[e] - m) : 0.f;
        s += e0[e] + e1[e];
    }
    #pragma unroll
    for (int off = 32; off > 0; off >>= 1) s += __shfl_xor(s, off);
    __shared__ float reds[4];
    if (lane == 0) reds[wid] = s;
    __syncthreads();   // loads retired before in-place writes
    s = reds[0] + reds[1] + reds[2] + reds[3];
    const float rinv = 1.f / s;

    unsigned short* P = (unsigned short*)row;
    u16x4 o0, o1;
    o0.x = f2b(e0[0] * rinv); o0.y = f2b(e0[1] * rinv);
    o0.z = f2b(e0[2] * rinv); o0.w = f2b(e0[3] * rinv);
    o1.x = f2b(e1[0] * rinv); o1.y = f2b(e1[1] * rinv);
    o1.z = f2b(e1[2] * rinv); o1.w = f2b(e1[3] * rinv);
    *(u16x4*)&P[j0] = o0;
    *(u16x4*)&P[j1] = o1;
}

// ---------------------------------------------------------------------------
// Split-K fixup: out rows [1024,2048) per batch += pv2 (same indexing).
__global__ __launch_bounds__(256)
void add_upper(float* __restrict__ out, const float* __restrict__ pv2) {
    const long gi = (long)blockIdx.x * 256 + threadIdx.x;   // f32x4 index
    const long z = gi >> 18;                                 // 262144 f4 per z
    const long r = gi & 262143;
    const long idx = z * 2097152 + 1048576 + r * 4;
    f32x4 a = *(const f32x4*)(out + idx);
    f32x4 b = *(const f32x4*)(pv2 + idx);
    a.x += b.x; a.y += b.y; a.z += b.z; a.w += b.w;
    *(f32x4*)(out + idx) = a;
}

// ---------------------------------------------------------------------------
extern "C" void kernel_launch(void* const* d_in, const int* in_sizes, int n_in,
                              void* d_out, int out_size, void* d_ws, size_t ws_size,
                              hipStream_t stream) {
    const float* x  = (const float*)d_in[0];
    const float* Wq = (const float*)d_in[1];
    const float* Wk = (const float*)d_in[2];
    const float* Wv = (const float*)d_in[3];
    float* out = (float*)d_out;
    char* ws = (char*)d_ws;
    const size_t MiB = 1ull << 20;

    unsigned short* xb  = (unsigned short*)(ws);              // [8192][1024] bf16
    unsigned short* WT  = (unsigned short*)(ws + 16 * MiB);   // 3x [1024][1024] bf16
    unsigned short* Qb  = (unsigned short*)(ws + 22 * MiB);   // [4][2048][1024]
    unsigned short* Kb  = (unsigned short*)(ws + 38 * MiB);   // [4][2048][1024]
    unsigned short* VbT = (unsigned short*)(ws + 54 * MiB);   // [1024][8192]
    float* scores       = (float*)(ws + 70 * MiB);            // nb x [2048][2048] fp32
    // pv2 reuses xb+WT+Qb (dead after scores in the nb=4 path): 33.5 MiB at ws+0
    float* pv2          = (float*)(ws);

    int nb;
    if      (ws_size >= (70 + 64) * MiB) nb = 4;
    else if (ws_size >= (70 + 32) * MiB) nb = 2;
    else                                 nb = 1;
    const bool splitK = (nb == 4);   // pv2 aliasing is only safe single-chunk

    const int LDSA = 3 * 16384 * 2;                 // 96 KiB
    const int LDSB = 3 * (128 + 256) * 64 * 2;      // 144 KiB
    hipFuncSetAttribute((const void*)gemm_A<0,false,false>,
                        hipFuncAttributeMaxDynamicSharedMemorySize, LDSA);
    hipFuncSetAttribute((const void*)gemm_A<1,true,false>,
                        hipFuncAttributeMaxDynamicSharedMemorySize, LDSA);
    hipFuncSetAttribute((const void*)gemm_A<1,false,true>,
                        hipFuncAttributeMaxDynamicSharedMemorySize, LDSA);
    hipFuncSetAttribute((const void*)gemm_B,
                        hipFuncAttributeMaxDynamicSharedMemorySize, LDSB);

    // 1) converts
    cvt_kernel<<<8192, 256, 0, stream>>>(x, xb);
    transW_kernel<<<dim3(32, 32, 3), 256, 0, stream>>>(Wq, Wk, Wv, WT);

    // 2) projections
    // Q,K = x*W : 256x256 tiles, grid 32x4x2 = 256 blocks (z: Wq->Qb, Wk->Kb)
    gemm_A<0,false,false><<<dim3(32, 4, 2), 512, LDSA, stream>>>(
        xb, 1024, 0L, WT, 1024, (long)1024 * 1024,
        Qb, 1024, (long)8192 * 1024, 1024, 1.0f, nullptr, 0, 0);
    // V^T = Wv^T * x^T -> [1024][8192] : kernel B, grid 8x32 = 256 blocks
    gemm_B<<<dim3(8, 32), 512, LDSB, stream>>>(
        WT + (long)2 * 1024 * 1024, 1024, xb, 1024, VbT, 8192, 1024);

    // 3) attention
    const float alpha = 0.03125f;   // 1/sqrt(1024)
    for (int b0 = 0; b0 < NBATCH; b0 += nb) {
        const int nz = (NBATCH - b0 < nb) ? (NBATCH - b0) : nb;
        // scores = Q K^T * alpha : 256x256 causal-skip (bn>bm), 144 active/4z
        gemm_A<1,true,false><<<dim3(8, 8, nz), 512, LDSA, stream>>>(
            Qb + (long)b0 * S_LEN * D_DIM, 1024, (long)S_LEN * D_DIM,
            Kb + (long)b0 * S_LEN * D_DIM, 1024, (long)S_LEN * D_DIM,
            scores, S_LEN, (long)S_LEN * S_LEN, 1024, alpha, nullptr, 0, 0);
        // softmax rows (in-place bf16 P, zero-filled past diagonal)
        softmax_rows<<<dim3(S_LEN, nz), 256, 0, stream>>>(scores);
        // O = P V : split-K balanced (x<8: K<=1024 -> out; x>=8: K>1024 -> pv2)
        if (splitK) {
            gemm_A<1,false,true><<<dim3(12, 4, nz), 512, LDSA, stream>>>(
                (const unsigned short*)scores, 2 * S_LEN, 2L * S_LEN * S_LEN,
                VbT + (long)b0 * S_LEN, 8192, (long)S_LEN,
                out + (long)b0 * S_LEN * D_DIM, 1024, (long)S_LEN * D_DIM,
                2048, 1.0f, pv2, 8, 1024);
            add_upper<<<4096, 256, 0, stream>>>(out, pv2);
        } else {
            gemm_A<1,false,true><<<dim3(8, 4, nz), 512, LDSA, stream>>>(
                (const unsigned short*)scores, 2 * S_LEN, 2L * S_LEN * S_LEN,
                VbT + (long)b0 * S_LEN, 8192, (long)S_LEN,
                out + (long)b0 * S_LEN * D_DIM, 1024, (long)S_LEN * D_DIM,
                2048, 1.0f, nullptr, 8, 1 << 30);
        }
    }
}